// Round 3
// baseline (492.265 us; speedup 1.0000x reference)
//
#include <hip/hip_runtime.h>
#include <stdint.h>

#define B_ 8
#define T_ 256
#define S_ 512
#define D_ 768
#define H_ 8
#define V_ 32000
#define BLOCK 512
#define NWAVE (BLOCK / 64)      // 8 waves
#define NF4 (V_ / 4)            // 8000 float4 per row
#define SLOTS 1024              // hash slots (max 512 keys -> load factor 0.5)
#define EMPTYK 0xFFFFFFFFu
#define BMW ((V_ + 31) / 32)    // 1000 bitmap words

typedef float vf4 __attribute__((ext_vector_type(4)));  // native vector: NT load/store OK

static __device__ __forceinline__ float e4(vf4 v) {
    return __expf(v.x) + __expf(v.y) + __expf(v.z) + __expf(v.w);
}

__global__ __launch_bounds__(BLOCK, 8) void ptrgen_f32(
    const float* __restrict__ dec,   // (B,T,D)
    const float* __restrict__ fin,   // (B,T,V)
    const float* __restrict__ attw,  // (B,H,T,S)
    const int* __restrict__ enc,     // (B,S)
    const float* __restrict__ W,     // (D,1)
    const float* __restrict__ bbias, // (1,)
    float* __restrict__ out)         // (B,T,V)
{
    // ~12.5 KB LDS total -> residency is wave-capped at 4 blocks/CU (32 waves)
    __shared__ unsigned int hkey[SLOTS];   // 4 KB
    __shared__ float        hval[SLOTS];   // 4 KB (f32: better accuracy than old f16)
    __shared__ unsigned int bmap[BMW];     // 4000 B
    __shared__ float sred[3 * NWAVE];
    __shared__ float sbc[3];

    const int tid = threadIdx.x;
    const int bid = blockIdx.x;  // row = b*T + t
    const int b = bid >> 8;      // T_ = 256
    const int t = bid & 255;

    // ---- zero bitmap + hash (fast: ~12.5 KB) ----
#pragma unroll
    for (int i = tid; i < SLOTS; i += BLOCK) { hkey[i] = EMPTYK; hval[i] = 0.0f; }
    for (int i = tid; i < BMW; i += BLOCK) bmap[i] = 0u;

    // ---- p_gen dot partial: D=768, 512 threads -> 1 or 2 dims each ----
    float pp = dec[(size_t)bid * D_ + tid] * W[tid];
    if (tid < D_ - BLOCK)  // 256
        pp += dec[(size_t)bid * D_ + BLOCK + tid] * W[BLOCK + tid];

    // ---- attention: ae = exp(mean_h attw); S_ == BLOCK so every thread has one ----
    const float* ab = attw + ((size_t)(b * H_) * T_ + t) * S_ + tid;
    float s = 0.0f;
#pragma unroll
    for (int h = 0; h < H_; ++h) s += ab[(size_t)h * (T_ * S_)];
    const float ae = __expf(s * (1.0f / H_));
    const int token = enc[b * S_ + tid];

    __syncthreads();  // LDS zeroed before scatter

    // ---- scatter: bitmap bit + hash insert (f32 ds_add) ----
    atomicOr(&bmap[token >> 5], 1u << (token & 31));
    {
        unsigned int h = ((unsigned int)token * 2654435761u) >> 22;  // top 10 bits
        for (;;) {
            unsigned int prev = atomicCAS(&hkey[h], EMPTYK, (unsigned int)token);
            if (prev == EMPTYK || prev == (unsigned int)token) {
                atomicAdd(&hval[h], ae);
                break;
            }
            h = (h + 1) & (SLOTS - 1);
        }
    }

    // ---- pass 1: sum exp over the row (plain loads: populate L2/L3 for pass 2).
    //      Scatter latency above hides under these loads. ----
    const vf4* rowf = (const vf4*)(fin + (size_t)bid * V_);
    float lsum = 0.0f;
#pragma unroll 5
    for (int i = 0; i < 15; ++i) lsum += e4(rowf[tid + i * BLOCK]);
    if (tid < NF4 - 15 * BLOCK)  // 320
        lsum += e4(rowf[tid + 15 * BLOCK]);

    // ---- one triple block reduction: (pp, ae, lsum) over 8 waves ----
    const int lane = tid & 63, wid = tid >> 6;
    float v0 = pp, v1 = ae, v2 = lsum;
#pragma unroll
    for (int o = 32; o; o >>= 1) {
        v0 += __shfl_xor(v0, o, 64);
        v1 += __shfl_xor(v1, o, 64);
        v2 += __shfl_xor(v2, o, 64);
    }
    if (lane == 0) {
        sred[wid] = v0;
        sred[NWAVE + wid] = v1;
        sred[2 * NWAVE + wid] = v2;
    }
    __syncthreads();  // also orders the LDS scatter vs pass-2 reads
    if (wid == 0) {
        float a0 = (lane < NWAVE) ? sred[lane] : 0.0f;
        float a1 = (lane < NWAVE) ? sred[NWAVE + lane] : 0.0f;
        float a2 = (lane < NWAVE) ? sred[2 * NWAVE + lane] : 0.0f;
#pragma unroll
        for (int o = 4; o; o >>= 1) {
            a0 += __shfl_xor(a0, o, 64);
            a1 += __shfl_xor(a1, o, 64);
            a2 += __shfl_xor(a2, o, 64);
        }
        if (lane == 0) { sbc[0] = a0; sbc[1] = a1; sbc[2] = a2; }
    }
    __syncthreads();

    const float p_gen  = 1.0f / (1.0f + __expf(-(sbc[0] + bbias[0])));
    const float inv_l  = p_gen / sbc[2];           // p_gen / sum exp
    const float cscale = (1.0f - p_gen) / sbc[1];  // (1-p_gen) / sum attention-exp

    // ---- pass 2: re-read row (NT: L2/L3-hot, evict-first), bitmap fast-path,
    //      hash probe only for the ~512/32000 slots with copy mass ----
    vf4* outp = (vf4*)(out + (size_t)bid * V_);

    auto hget = [&](int idx) -> float {
        unsigned int h = ((unsigned int)idx * 2654435761u) >> 22;
        for (;;) {
            unsigned int k = hkey[h];
            if (k == (unsigned int)idx) return hval[h];
            if (k == EMPTYK) return 0.0f;
            h = (h + 1) & (SLOTS - 1);
        }
    };

#pragma unroll 4
    for (int c = tid; c < NF4; c += BLOCK) {
        const vf4 x = __builtin_nontemporal_load(rowf + c);
        // ids 4c..4c+3 -> nibble (c&7)*4 of bitmap word c>>3 (broadcast read)
        const unsigned int nib = (bmap[c >> 3] >> ((c & 7) * 4)) & 0xFu;
        float c0 = 0.0f, c1 = 0.0f, c2 = 0.0f, c3 = 0.0f;
        if (nib) {  // rare: ~6% of chunks
            if (nib & 1u) c0 = hget(4 * c + 0);
            if (nib & 2u) c1 = hget(4 * c + 1);
            if (nib & 4u) c2 = hget(4 * c + 2);
            if (nib & 8u) c3 = hget(4 * c + 3);
        }
        vf4 y;
        y.x = __logf(fmaf(__expf(x.x), inv_l, fmaf(c0, cscale, 0.001f)));
        y.y = __logf(fmaf(__expf(x.y), inv_l, fmaf(c1, cscale, 0.001f)));
        y.z = __logf(fmaf(__expf(x.z), inv_l, fmaf(c2, cscale, 0.001f)));
        y.w = __logf(fmaf(__expf(x.w), inv_l, fmaf(c3, cscale, 0.001f)));
        __builtin_nontemporal_store(y, outp + c);
    }
}

extern "C" void kernel_launch(void* const* d_in, const int* in_sizes, int n_in,
                              void* d_out, int out_size, void* d_ws, size_t ws_size,
                              hipStream_t stream) {
    const float* dec   = (const float*)d_in[0];
    const float* fin   = (const float*)d_in[1];
    const float* attw  = (const float*)d_in[2];
    const int*   enc   = (const int*)d_in[3];
    const float* W     = (const float*)d_in[4];
    const float* bbias = (const float*)d_in[5];
    float* out = (float*)d_out;

    ptrgen_f32<<<B_ * T_, BLOCK, 0, stream>>>(dec, fin, attw, enc, W, bbias, out);
}